// Round 1
// baseline (267.119 us; speedup 1.0000x reference)
//
#include <hip/hip_runtime.h>
#include <math.h>

#define BINS 30

static constexpr int BLOCK  = 256;
static constexpr int GRID   = 2048;  // 8 resident blocks/CU (17 KiB LDS, 64 VGPR) x 256 CUs
static constexpr int SLOTS  = 32;    // 30 bins + slot 30 = trash (out-of-range), 31 pad
static constexpr int COLS   = 128;   // 2 threads (different waves) share a column via ds_add
static constexpr int UNROLL = 4;     // float4 loads per array per superiteration

typedef float f32x4 __attribute__((ext_vector_type(4)));  // native vec: OK for nontemporal builtins

__device__ __forceinline__ float wave_sum(float v) {
    #pragma unroll
    for (int o = 32; o > 0; o >>= 1) v += __shfl_xor(v, o, 64);
    return v;
}

// Per-column packed histograms in LDS: h[slot*COLS + (tid&127)] holds
// x-count in bits 0..15 (+1), y-count in bits 16..31 (+65536).
// ds_add_u32 fire-and-forget; bank = col%32 (2-way aliasing within a wave
// = free per m136; cross-wave same-address collisions handled by the
// atomic unit and are rare with random data).
//
// R5 = R4 with the occupancy fix: COLS 256->128 halves LDS to 17 KiB and
// __launch_bounds__(256,8) caps VGPRs at 64, lifting residency from
// 4 blocks/CU (16 waves, 50%) to 8 blocks/CU (32 waves, 100%) so the
// nontemporal (L2-bypass, ~900 cyc) load latency is hidden by TLP.
// Exactness: x-count per entry <= 2 threads * 64 vals = 128; per-block
// per-slot column sum <= 2^25/2048 = 16384 < 2^16, so packed u32 sums exact.
__global__ __launch_bounds__(BLOCK, 8) void hist_kernel(
        const float* __restrict__ x, const float* __restrict__ y,
        int n4, unsigned int* __restrict__ g_hist)
{
    __shared__ unsigned int h[SLOTS * COLS];      // 16 KiB
    __shared__ unsigned int partial[BLOCK];       // +1 KiB
    const int tid = threadIdx.x;
    const int col = tid & (COLS - 1);

    #pragma unroll
    for (int i = 0; i < (SLOTS * COLS) / BLOCK; ++i) h[i * BLOCK + tid] = 0u;
    __syncthreads();

    const f32x4* __restrict__ x4 = (const f32x4*)x;
    const f32x4* __restrict__ y4 = (const f32x4*)y;

    // torch.histc: idx = floor((v+4)*3.75) clipped to [0,29]; |v|>4 (or NaN) -> trash slot 30
    #define PROC(v, inc) {                                              \
        float q = ((v) + 4.0f) * 3.75f;                                 \
        int idx = (int)q;                                               \
        idx = idx > 29 ? 29 : idx;        /* v == 4.0 -> last bin */    \
        bool valid = fabsf(v) <= 4.0f;                                  \
        int slot = valid ? idx : 30;                                    \
        atomicAdd(&h[slot * COLS + col], (inc));  /* ds_add_u32 */      \
    }
    #define PROC4(f, inc) { PROC((f).x, inc) PROC((f).y, inc) PROC((f).z, inc) PROC((f).w, inc) }

    const int span   = GRID * BLOCK * UNROLL;      // float4 per superiteration
    const int chunk0 = blockIdx.x * (BLOCK * UNROLL);

    for (int chunk = chunk0; chunk + BLOCK * UNROLL <= n4; chunk += span) {
        f32x4 a[UNROLL], b[UNROLL];
        #pragma unroll
        for (int j = 0; j < UNROLL; ++j)
            a[j] = __builtin_nontemporal_load(&x4[chunk + j * BLOCK + tid]);
        #pragma unroll
        for (int j = 0; j < UNROLL; ++j)
            b[j] = __builtin_nontemporal_load(&y4[chunk + j * BLOCK + tid]);
        #pragma unroll
        for (int j = 0; j < UNROLL; ++j) {
            PROC4(a[j], 1u)
            PROC4(b[j], 65536u)
        }
    }

    // Tail (empty for the benchmark's 2^23 float4s; kept for generality)
    const int tail_start = n4 - (n4 % span);
    for (int i = tail_start + blockIdx.x * BLOCK + tid; i < n4; i += GRID * BLOCK) {
        f32x4 a = x4[i], b = y4[i];
        PROC4(a, 1u)
        PROC4(b, 65536u)
    }
    #undef PROC4
    #undef PROC
    __syncthreads();

    // Reduce 128 columns per slot (packed u32 sums exact).
    // 8 groups of 32 threads; group g sums 16 columns of slot (tid&31).
    // Bank = col%32 (slot*COLS is bank-aligned): 2-way per wave = free.
    const int slot = tid & 31;
    const int g    = tid >> 5;
    unsigned int s = 0;
    #pragma unroll
    for (int c = 0; c < 16; ++c) {
        int cc = g * 16 + ((c + tid) & 15);
        s += h[slot * COLS + cc];
    }
    partial[tid] = s;
    __syncthreads();
    if (tid < 32) {
        unsigned int tot = 0;
        #pragma unroll
        for (int gg = 0; gg < 8; ++gg) tot += partial[gg * 32 + tid];
        if (tid < BINS) {
            atomicAdd(&g_hist[tid],      tot & 0xFFFFu);  // x histogram
            atomicAdd(&g_hist[32 + tid], tot >> 16);      // y histogram
        }
    }
}

__global__ void finalize_kernel(const unsigned int* __restrict__ g_hist,
                                float* __restrict__ out)
{
    const int t = threadIdx.x;
    const bool active = t < BINS;
    float hx = active ? (float)g_hist[t]      : 0.0f;
    float hy = active ? (float)g_hist[32 + t] : 0.0f;
    float hj = hx + hy;                      // joint = hist_x + hist_y exactly

    float Sx = wave_sum(hx);
    float Sy = wave_sum(hy);
    float Sj = wave_sum(hj);

    float px = hx / Sx;
    float py = hy / Sy;
    float jp = hj / Sj;

    // mi = 30 * sum_j jp_j*(log jp_j - log py_j) - (sum_j jp_j) * (sum_i log px_i)
    float term = active ? jp * (logf(jp) - logf(py)) : 0.0f;
    float lpx  = active ? logf(px) : 0.0f;
    float sjp  = wave_sum(active ? jp : 0.0f);

    float st = wave_sum(term);
    float sl = wave_sum(lpx);
    if (t == 0) out[0] = -((float)BINS * st - sjp * sl);
}

extern "C" void kernel_launch(void* const* d_in, const int* in_sizes, int n_in,
                              void* d_out, int out_size, void* d_ws, size_t ws_size,
                              hipStream_t stream) {
    const float* x = (const float*)d_in[0];
    const float* y = (const float*)d_in[1];
    const int n = in_sizes[0];               // 2^25, divisible by 4
    unsigned int* g_hist = (unsigned int*)d_ws;

    (void)hipMemsetAsync(d_ws, 0, 64 * sizeof(unsigned int), stream);  // ws is poisoned 0xAA
    hist_kernel<<<GRID, BLOCK, 0, stream>>>(x, y, n >> 2, g_hist);
    finalize_kernel<<<1, 64, 0, stream>>>(g_hist, (float*)d_out);
}